// Round 7
// baseline (1598.447 us; speedup 1.0000x reference)
//
#include <hip/hip_runtime.h>

#define N_CODES 512
#define D 32
#define NVEC (8192 * 64)          // 524288 vectors
#define ZQ_ELEMS (NVEC * D)
#define MARGIN_TRIG 7e-5f
#define SA (-1.0f / 16.0f)        // A = SA*z   (power of 2, exact)
#define SB (32.0f)                // B = SB*w   -> A*B sums to -2 z.w

typedef _Float16 half8 __attribute__((ext_vector_type(8)));
typedef float f32x4 __attribute__((ext_vector_type(4)));

// ws: @0 double lossacc | @8 uint flagcnt | @64 float ww[512] | @2112 bfrag (32768)
//     | @36864 int worklist[...]
#define STAGE_F4 2176             // (2048 + 32768) / 16
#define WL_OFF 36864
// LDS: ww @0 (2048) | bfrag @2048 (32768) | scratch @34816 (256*16) = 38912 B

__global__ void vq_prep(const float* __restrict__ cb, float* __restrict__ ww,
                        half8* __restrict__ bfrag, double* __restrict__ lossacc,
                        unsigned* __restrict__ flagcnt) {
    int gid = blockIdx.x * 256 + threadIdx.x;   // 8 x 256 = 2048
    if (gid == 0) { *lossacc = 0.0; *flagcnt = 0u; }
    if (gid >= 2048) return;
    int t = gid >> 6, l = gid & 63;
    int code = t * 16 + (l & 15), koff = (l >> 4) * 8;
    const float* w = cb + (size_t)code * D + koff;
    half8 h;
#pragma unroll
    for (int j = 0; j < 8; ++j) h[j] = (_Float16)(SB * w[j]);
    bfrag[t * 64 + l] = h;                      // MFMA B-fragment lane order
    if (koff == 0) {                            // platonic ||w||^2 -> f32
        const float* wr = cb + (size_t)code * D;
        double s = 0.0;
#pragma unroll
        for (int d = 0; d < D; ++d) s = fma((double)wr[d], (double)wr[d], s);
        ww[code] = (float)s;
    }
}

__global__ __launch_bounds__(256, 4) void vq_main(
        const float* __restrict__ z, const float* __restrict__ cbf,
        const float4* __restrict__ stage_src,   // ws+64
        float* __restrict__ zq, float* __restrict__ idxo,
        double* __restrict__ lossacc, unsigned* __restrict__ flagcnt,
        int* __restrict__ worklist, int wl_cap) {
    __shared__ __align__(16) char smem[38912];
    const int tid = threadIdx.x;

    {   // stage ww + B-fragments into LDS
        float4* s4 = (float4*)smem;
#pragma unroll
        for (int i = 0; i < 9; ++i) {
            int k = i * 256 + tid;
            if (k < STAGE_F4) s4[k] = stage_src[k];
        }
    }

    const float* lds_ww = (const float*)smem;
    const char* lds_bf = smem + 2048;
    float4* scratch = (float4*)(smem + 34816);   // [256 rows] (m1, m2, idx, zz)

    const int l = tid & 63, wv = tid >> 6;
    const int g16 = l & 15, kg = l >> 4, koff = kg * 8;
    const int vblock = blockIdx.x * 256;         // block owns 256 rows

    __syncthreads();   // staging visible

#pragma unroll 1
    for (int mt = 0; mt < 4; ++mt) {
        const int rbase = wv * 64 + mt * 16;     // rows rbase..rbase+15 (in block)
        const float* zp = z + (size_t)(vblock + rbase + g16) * D + koff;
        float4 a0 = *(const float4*)zp;
        float4 a1 = *(const float4*)(zp + 4);
        half8 A;
        A[0] = (_Float16)(a0.x * SA); A[1] = (_Float16)(a0.y * SA);
        A[2] = (_Float16)(a0.z * SA); A[3] = (_Float16)(a0.w * SA);
        A[4] = (_Float16)(a1.x * SA); A[5] = (_Float16)(a1.y * SA);
        A[6] = (_Float16)(a1.z * SA); A[7] = (_Float16)(a1.w * SA);
        float ss = 0.f;
        ss = fmaf(a0.x, a0.x, ss); ss = fmaf(a0.y, a0.y, ss);
        ss = fmaf(a0.z, a0.z, ss); ss = fmaf(a0.w, a0.w, ss);
        ss = fmaf(a1.x, a1.x, ss); ss = fmaf(a1.y, a1.y, ss);
        ss = fmaf(a1.z, a1.z, ss); ss = fmaf(a1.w, a1.w, ss);
        ss += __shfl_xor(ss, 16, 64);            // sum the 4 koff chunks
        ss += __shfl_xor(ss, 32, 64);

        float m1[4], m2[4]; int i1[4];
#pragma unroll
        for (int r = 0; r < 4; ++r) { m1[r] = 1e30f; m2[r] = 1e30f; i1[r] = 0; }

#pragma unroll 4
        for (int t = 0; t < 32; ++t) {
            half8 B = *(const half8*)(lds_bf + t * 1024 + l * 16);
            float wwv = lds_ww[t * 16 + g16];
            int nl = t * 16 + g16;
            f32x4 acc = {wwv, wwv, wwv, wwv};    // C-init = ||w||^2 -> acc = score
            acc = __builtin_amdgcn_mfma_f32_16x16x32_f16(A, B, acc, 0, 0, 0);
#pragma unroll
            for (int r = 0; r < 4; ++r) {
                float s = acc[r];
                m2[r] = fminf(m2[r], fmaxf(s, m1[r]));
                bool c = s < m1[r];
                i1[r] = c ? nl : i1[r];
                m1[r] = fminf(m1[r], s);
            }
        }

        // reduce across the 16 code-lanes of each row-group
#pragma unroll
        for (int r = 0; r < 4; ++r) {
            float a1v = m1[r], a2v = m2[r]; int ai = i1[r];
#pragma unroll
            for (int dd = 1; dd <= 8; dd <<= 1) {
                float o1 = __shfl_xor(a1v, dd, 64);
                float o2 = __shfl_xor(a2v, dd, 64);
                int oi = __shfl_xor(ai, dd, 64);
                a2v = fminf(fminf(a2v, o2), fmaxf(a1v, o1));
                bool take = (o1 < a1v) || (o1 == a1v && oi < ai);
                ai = take ? oi : ai;
                a1v = fminf(a1v, o1);
            }
            m1[r] = a1v; m2[r] = a2v; i1[r] = ai;
        }

        // row table: row rbase + 4*kg + r  (holder lane g16==r)
#pragma unroll
        for (int r = 0; r < 4; ++r)
            if (g16 == r) {
                float* sp = (float*)&scratch[rbase + 4 * kg + r];
                sp[0] = m1[r]; sp[1] = m2[r]; sp[2] = __int_as_float(i1[r]);
            }
        if (kg == 0)
            ((float*)&scratch[rbase + g16])[3] = ss;   // ||z||^2
    }
    __syncthreads();

    // ---- epilogue (block scope; no f64 rescan here) ----
    float4 my = scratch[tid];                    // row tid of this block

    // near-tie rows -> global worklist (resolved by vq_fixup kernel)
    {
        bool flag = (my.y - my.x) <= MARGIN_TRIG;
        unsigned long long mask = __ballot(flag);
        if (mask) {
            int base = 0;
            if (l == 0) base = (int)atomicAdd(flagcnt, (unsigned)__popcll(mask));
            base = __shfl(base, 0, 64);
            if (flag) {
                int pos = base + (int)__popcll(mask & ((1ull << l) - 1ull));
                if (pos < wl_cap) worklist[pos] = vblock + tid;
            }
        }
    }

    // loss: ||z-q||^2 = ||z||^2 + s_win
    {
        double contrib = (double)my.x + (double)my.w;
#pragma unroll
        for (int off = 32; off; off >>= 1) contrib += __shfl_down(contrib, off, 64);
        if (l == 0) atomicAdd(lossacc, contrib);
    }
    // indices: 1KB contiguous per block
    idxo[vblock + tid] = (float)__float_as_int(my.z);
    // z_q: 256 threads x 8 iters cover 256 rows x 32 floats, fully contiguous
    {
        const float4* cb4 = (const float4*)cbf;
        float4* zq4 = (float4*)zq;
        const int c = tid & 7;
#pragma unroll
        for (int it = 0; it < 8; ++it) {
            int r = it * 32 + (tid >> 3);
            int win = __float_as_int(((const float*)scratch)[r * 4 + 2]);
            float4 val = cb4[(size_t)win * 8 + c];
            zq4[(size_t)(vblock + r) * 8 + c] = val;
        }
    }
}

// cold path: exact wave-parallel rescan of flagged rows (register-hungry is OK here)
__global__ void vq_fixup(const float* __restrict__ z, const float* __restrict__ cbf,
                         const float* __restrict__ c32g,
                         float* __restrict__ zq, float* __restrict__ idxo,
                         const unsigned* __restrict__ flagcnt,
                         const int* __restrict__ worklist, int wl_cap) {
    int cnt = (int)*flagcnt; if (cnt > wl_cap) cnt = wl_cap;
    const int l = threadIdx.x & 63;
    const int wave = (blockIdx.x * blockDim.x + threadIdx.x) >> 6;
    const int nwaves = (gridDim.x * blockDim.x) >> 6;

    for (int e = wave; e < cnt; e += nwaves) {
        int v = worklist[e];
        const float* zv = z + (size_t)v * D;        // uniform addr -> broadcast
        double Ad = 0.0;
#pragma unroll
        for (int q = 0; q < 8; ++q) {
            float4 zzv = *(const float4*)(zv + q * 4);
            Ad = fma((double)zzv.x, (double)zzv.x, Ad);
            Ad = fma((double)zzv.y, (double)zzv.y, Ad);
            Ad = fma((double)zzv.z, (double)zzv.z, Ad);
            Ad = fma((double)zzv.w, (double)zzv.w, Ad);
        }
        float Af = (float)Ad;
        float best = 1e30f; int bi = 0;
#pragma unroll
        for (int j = 0; j < 8; ++j) {
            int c = l * 8 + j;                      // lane-major => index-ordered
            const float* w = cbf + (size_t)c * D;
            double bd = 0.0;
#pragma unroll
            for (int q = 0; q < 8; ++q) {
                float4 zzv = *(const float4*)(zv + q * 4);
                float4 wq = *(const float4*)(w + q * 4);
                bd = fma((double)zzv.x, (double)wq.x, bd);
                bd = fma((double)zzv.y, (double)wq.y, bd);
                bd = fma((double)zzv.z, (double)wq.z, bd);
                bd = fma((double)zzv.w, (double)wq.w, bd);
            }
            float B32 = (float)bd;                  // platonic dot
            float dq = __fadd_rn(__fsub_rn(Af, __fmul_rn(2.0f, B32)), c32g[c]);
            if (dq < best) { best = dq; bi = c; }
        }
#pragma unroll
        for (int dd = 1; dd < 64; dd <<= 1) {
            float ob = __shfl_xor(best, dd, 64);
            int obi = __shfl_xor(bi, dd, 64);
            bool take = (ob < best) || (ob == best && obi < bi);
            best = take ? ob : best; bi = take ? obi : bi;
        }
        if (l == 0) idxo[v] = (float)bi;
        if (l < 8) {                                // one full 128B line
            float4 val = ((const float4*)cbf)[(size_t)bi * 8 + l];
            ((float4*)zq)[(size_t)v * 8 + l] = val;
        }
    }
}

__global__ void vq_final(const double* __restrict__ lossacc,
                         float* __restrict__ loss_out) {
    *loss_out = (float)(1.25 * (*lossacc) / (double)ZQ_ELEMS);
}

extern "C" void kernel_launch(void* const* d_in, const int* in_sizes, int n_in,
                              void* d_out, int out_size, void* d_ws, size_t ws_size,
                              hipStream_t stream) {
    const float* z  = (const float*)d_in[0];
    const float* cb = (const float*)d_in[1];
    float* out  = (float*)d_out;
    float* zq   = out;
    float* idxo = out + ZQ_ELEMS;
    float* loss = out + ZQ_ELEMS + NVEC;
    double*   lossacc = (double*)d_ws;
    unsigned* flagcnt = (unsigned*)((char*)d_ws + 8);
    float*    ww      = (float*)((char*)d_ws + 64);
    half8*    bfrag   = (half8*)((char*)d_ws + 2112);
    const float4* stage_src = (const float4*)((char*)d_ws + 64);
    int*      worklist = (int*)((char*)d_ws + WL_OFF);
    long long avail = (long long)ws_size - WL_OFF;
    int wl_cap = avail > 0 ? (int)(avail / 4 < NVEC ? avail / 4 : NVEC) : 0;

    vq_prep<<<8, 256, 0, stream>>>(cb, ww, bfrag, lossacc, flagcnt);
    vq_main<<<NVEC / 256, 256, 0, stream>>>(z, cb, stage_src, zq, idxo,
                                            lossacc, flagcnt, worklist, wl_cap);
    vq_fixup<<<128, 256, 0, stream>>>(z, cb, ww, zq, idxo, flagcnt, worklist, wl_cap);
    vq_final<<<1, 1, 0, stream>>>(lossacc, loss);
}

// Round 8
// 422.621 us; speedup vs baseline: 3.7822x; 3.7822x over previous
//
#include <hip/hip_runtime.h>

#define N_CODES 512
#define D 32
#define NVEC (8192 * 64)          // 524288 vectors
#define ZQ_ELEMS (NVEC * D)
#define MARGIN_TRIG 7e-5f
#define SA (-1.0f / 16.0f)        // A = SA*z   (power of 2, exact)
#define SB (32.0f)                // B = SB*w   -> A*B sums to -2 z.w

typedef _Float16 half8 __attribute__((ext_vector_type(8)));
typedef float f32x4 __attribute__((ext_vector_type(4)));

// ws: @0 double lossacc | @8 uint flagcnt | @64 float ww[512] | @2112 bfrag (32768)
//     | @36864 int worklist[...]
#define STAGE_F4 2176             // (2048 + 32768) / 16
#define WL_OFF 36864
// LDS: ww @0 (2048) | bfrag @2048 (32768) | scratch @34816 (256*16) = 38912 B

__global__ void vq_prep(const float* __restrict__ cb, float* __restrict__ ww,
                        half8* __restrict__ bfrag, double* __restrict__ lossacc,
                        unsigned* __restrict__ flagcnt) {
    int gid = blockIdx.x * 256 + threadIdx.x;   // 8 x 256 = 2048
    if (gid == 0) { *lossacc = 0.0; *flagcnt = 0u; }
    if (gid >= 2048) return;
    int t = gid >> 6, l = gid & 63;
    int code = t * 16 + (l & 15), koff = (l >> 4) * 8;
    const float* w = cb + (size_t)code * D + koff;
    half8 h;
#pragma unroll
    for (int j = 0; j < 8; ++j) h[j] = (_Float16)(SB * w[j]);
    bfrag[t * 64 + l] = h;                      // MFMA B-fragment lane order
    if (koff == 0) {                            // platonic ||w||^2 -> f32
        const float* wr = cb + (size_t)code * D;
        double s = 0.0;
#pragma unroll
        for (int d = 0; d < D; ++d) s = fma((double)wr[d], (double)wr[d], s);
        ww[code] = (float)s;
    }
}

__global__ __launch_bounds__(256, 3) void vq_main(
        const float* __restrict__ z, const float* __restrict__ cbf,
        const float4* __restrict__ stage_src,   // ws+64
        float* __restrict__ zq, float* __restrict__ idxo,
        double* __restrict__ lossacc, unsigned* __restrict__ flagcnt,
        int* __restrict__ worklist, int wl_cap) {
    __shared__ __align__(16) char smem[38912];
    const int tid = threadIdx.x;

    {   // stage ww + B-fragments into LDS
        float4* s4 = (float4*)smem;
#pragma unroll
        for (int i = 0; i < 9; ++i) {
            int k = i * 256 + tid;
            if (k < STAGE_F4) s4[k] = stage_src[k];
        }
    }

    const float* lds_ww = (const float*)smem;
    const char* lds_bf = smem + 2048;
    float4* scratch = (float4*)(smem + 34816);   // [256 rows] (m1, m2, idx, zz)

    const int l = tid & 63, wv = tid >> 6;
    const int g16 = l & 15, kg = l >> 4, koff = kg * 8;
    const int vblock = blockIdx.x * 256;         // block owns 256 rows

    __syncthreads();   // staging visible

#pragma unroll 1
    for (int mt = 0; mt < 4; ++mt) {
        const int rbase = wv * 64 + mt * 16;     // rows rbase..rbase+15 (in block)
        const float* zp = z + (size_t)(vblock + rbase + g16) * D + koff;
        float4 a0 = *(const float4*)zp;
        float4 a1 = *(const float4*)(zp + 4);
        half8 A;
        A[0] = (_Float16)(a0.x * SA); A[1] = (_Float16)(a0.y * SA);
        A[2] = (_Float16)(a0.z * SA); A[3] = (_Float16)(a0.w * SA);
        A[4] = (_Float16)(a1.x * SA); A[5] = (_Float16)(a1.y * SA);
        A[6] = (_Float16)(a1.z * SA); A[7] = (_Float16)(a1.w * SA);
        float ss = 0.f;
        ss = fmaf(a0.x, a0.x, ss); ss = fmaf(a0.y, a0.y, ss);
        ss = fmaf(a0.z, a0.z, ss); ss = fmaf(a0.w, a0.w, ss);
        ss = fmaf(a1.x, a1.x, ss); ss = fmaf(a1.y, a1.y, ss);
        ss = fmaf(a1.z, a1.z, ss); ss = fmaf(a1.w, a1.w, ss);
        ss += __shfl_xor(ss, 16, 64);            // sum the 4 koff chunks
        ss += __shfl_xor(ss, 32, 64);

        float m1[4], m2[4]; int i1[4];
#pragma unroll
        for (int r = 0; r < 4; ++r) { m1[r] = 1e30f; m2[r] = 1e30f; i1[r] = 0; }

#pragma unroll 4
        for (int t = 0; t < 32; ++t) {
            half8 B = *(const half8*)(lds_bf + t * 1024 + l * 16);
            float wwv = lds_ww[t * 16 + g16];
            int nl = t * 16 + g16;
            f32x4 acc = {wwv, wwv, wwv, wwv};    // C-init = ||w||^2 -> acc = score
            acc = __builtin_amdgcn_mfma_f32_16x16x32_f16(A, B, acc, 0, 0, 0);
#pragma unroll
            for (int r = 0; r < 4; ++r) {
                float s = acc[r];
                m2[r] = fminf(m2[r], fmaxf(s, m1[r]));
                bool c = s < m1[r];
                i1[r] = c ? nl : i1[r];
                m1[r] = fminf(m1[r], s);
            }
        }

        // reduce across the 16 code-lanes of each row-group
#pragma unroll
        for (int r = 0; r < 4; ++r) {
            float a1v = m1[r], a2v = m2[r]; int ai = i1[r];
#pragma unroll
            for (int dd = 1; dd <= 8; dd <<= 1) {
                float o1 = __shfl_xor(a1v, dd, 64);
                float o2 = __shfl_xor(a2v, dd, 64);
                int oi = __shfl_xor(ai, dd, 64);
                a2v = fminf(fminf(a2v, o2), fmaxf(a1v, o1));
                bool take = (o1 < a1v) || (o1 == a1v && oi < ai);
                ai = take ? oi : ai;
                a1v = fminf(a1v, o1);
            }
            m1[r] = a1v; m2[r] = a2v; i1[r] = ai;
        }

        // row table: row rbase + 4*kg + r  (holder lane g16==r)
#pragma unroll
        for (int r = 0; r < 4; ++r)
            if (g16 == r) {
                float* sp = (float*)&scratch[rbase + 4 * kg + r];
                sp[0] = m1[r]; sp[1] = m2[r]; sp[2] = __int_as_float(i1[r]);
            }
        if (kg == 0)
            ((float*)&scratch[rbase + g16])[3] = ss;   // ||z||^2
    }
    __syncthreads();

    // ---- epilogue (block scope; no f64 rescan here) ----
    float4 my = scratch[tid];                    // row tid of this block

    // near-tie rows -> global worklist (resolved by vq_fixup kernel)
    {
        bool flag = (my.y - my.x) <= MARGIN_TRIG;
        unsigned long long mask = __ballot(flag);
        if (mask) {
            int base = 0;
            if (l == 0) base = (int)atomicAdd(flagcnt, (unsigned)__popcll(mask));
            base = __shfl(base, 0, 64);
            if (flag) {
                int pos = base + (int)__popcll(mask & ((1ull << l) - 1ull));
                if (pos < wl_cap) worklist[pos] = vblock + tid;
            }
        }
    }

    // loss: ||z-q||^2 = ||z||^2 + s_win
    {
        double contrib = (double)my.x + (double)my.w;
#pragma unroll
        for (int off = 32; off; off >>= 1) contrib += __shfl_down(contrib, off, 64);
        if (l == 0) atomicAdd(lossacc, contrib);
    }
    // indices: 1KB contiguous per block
    idxo[vblock + tid] = (float)__float_as_int(my.z);
    // z_q: 256 threads x 8 iters cover 256 rows x 32 floats, fully contiguous
    {
        const float4* cb4 = (const float4*)cbf;
        float4* zq4 = (float4*)zq;
        const int c = tid & 7;
#pragma unroll
        for (int it = 0; it < 8; ++it) {
            int r = it * 32 + (tid >> 3);
            int win = __float_as_int(((const float*)scratch)[r * 4 + 2]);
            float4 val = cb4[(size_t)win * 8 + c];
            zq4[(size_t)(vblock + r) * 8 + c] = val;
        }
    }
}

// cold path: exact wave-parallel rescan of flagged rows.
// __launch_bounds__(256,2) -> VGPR cap 256: room for z in regs + 2 unrolled
// code rows (~110 live) with ZERO spill (round-7 failure mode: default cap 64
// -> ~250 regs spilled -> scratch thrash evicted codebook from L2 -> 585MB HBM).
__global__ __launch_bounds__(256, 2) void vq_fixup(
        const float* __restrict__ z, const float* __restrict__ cbf,
        const float* __restrict__ c32g,
        float* __restrict__ zq, float* __restrict__ idxo,
        const unsigned* __restrict__ flagcnt,
        const int* __restrict__ worklist, int wl_cap) {
    int cnt = (int)*flagcnt; if (cnt > wl_cap) cnt = wl_cap;
    const int l = threadIdx.x & 63;
    const int wave = (blockIdx.x * blockDim.x + threadIdx.x) >> 6;
    const int nwaves = (gridDim.x * blockDim.x) >> 6;

    for (int e = wave; e < cnt; e += nwaves) {
        int v = worklist[e];
        const float* zv = z + (size_t)v * D;        // uniform addr -> broadcast
        float4 zr[8];                               // hoist z once (32 regs)
#pragma unroll
        for (int q = 0; q < 8; ++q) zr[q] = *(const float4*)(zv + q * 4);
        double Ad = 0.0;
#pragma unroll
        for (int q = 0; q < 8; ++q) {
            Ad = fma((double)zr[q].x, (double)zr[q].x, Ad);
            Ad = fma((double)zr[q].y, (double)zr[q].y, Ad);
            Ad = fma((double)zr[q].z, (double)zr[q].z, Ad);
            Ad = fma((double)zr[q].w, (double)zr[q].w, Ad);
        }
        float Af = (float)Ad;
        float best = 1e30f; int bi = 0;
#pragma unroll 2
        for (int j = 0; j < 8; ++j) {
            int c = l * 8 + j;                      // lane-major => index-ordered
            const float* w = cbf + (size_t)c * D;
            double bd = 0.0;
#pragma unroll
            for (int q = 0; q < 8; ++q) {
                float4 wq = *(const float4*)(w + q * 4);
                bd = fma((double)zr[q].x, (double)wq.x, bd);
                bd = fma((double)zr[q].y, (double)wq.y, bd);
                bd = fma((double)zr[q].z, (double)wq.z, bd);
                bd = fma((double)zr[q].w, (double)wq.w, bd);
            }
            float B32 = (float)bd;                  // platonic dot
            float dq = __fadd_rn(__fsub_rn(Af, __fmul_rn(2.0f, B32)), c32g[c]);
            if (dq < best) { best = dq; bi = c; }
        }
#pragma unroll
        for (int dd = 1; dd < 64; dd <<= 1) {
            float ob = __shfl_xor(best, dd, 64);
            int obi = __shfl_xor(bi, dd, 64);
            bool take = (ob < best) || (ob == best && obi < bi);
            best = take ? ob : best; bi = take ? obi : bi;
        }
        if (l == 0) idxo[v] = (float)bi;
        if (l < 8) {                                // one full 128B line
            float4 val = ((const float4*)cbf)[(size_t)bi * 8 + l];
            ((float4*)zq)[(size_t)v * 8 + l] = val;
        }
    }
}

__global__ void vq_final(const double* __restrict__ lossacc,
                         float* __restrict__ loss_out) {
    *loss_out = (float)(1.25 * (*lossacc) / (double)ZQ_ELEMS);
}

extern "C" void kernel_launch(void* const* d_in, const int* in_sizes, int n_in,
                              void* d_out, int out_size, void* d_ws, size_t ws_size,
                              hipStream_t stream) {
    const float* z  = (const float*)d_in[0];
    const float* cb = (const float*)d_in[1];
    float* out  = (float*)d_out;
    float* zq   = out;
    float* idxo = out + ZQ_ELEMS;
    float* loss = out + ZQ_ELEMS + NVEC;
    double*   lossacc = (double*)d_ws;
    unsigned* flagcnt = (unsigned*)((char*)d_ws + 8);
    float*    ww      = (float*)((char*)d_ws + 64);
    half8*    bfrag   = (half8*)((char*)d_ws + 2112);
    const float4* stage_src = (const float4*)((char*)d_ws + 64);
    int*      worklist = (int*)((char*)d_ws + WL_OFF);
    long long avail = (long long)ws_size - WL_OFF;
    int wl_cap = avail > 0 ? (int)(avail / 4 < NVEC ? avail / 4 : NVEC) : 0;

    vq_prep<<<8, 256, 0, stream>>>(cb, ww, bfrag, lossacc, flagcnt);
    vq_main<<<NVEC / 256, 256, 0, stream>>>(z, cb, stage_src, zq, idxo,
                                            lossacc, flagcnt, worklist, wl_cap);
    vq_fixup<<<128, 256, 0, stream>>>(z, cb, ww, zq, idxo, flagcnt, worklist, wl_cap);
    vq_final<<<1, 1, 0, stream>>>(lossacc, loss);
}

// Round 9
// 232.809 us; speedup vs baseline: 6.8659x; 1.8153x over previous
//
#include <hip/hip_runtime.h>

#define N_CODES 512
#define D 32
#define NVEC (8192 * 64)          // 524288 vectors
#define ZQ_ELEMS (NVEC * D)
#define NBLK (NVEC / 256)         // 2048 main blocks
#define MARGIN_TRIG 7e-5f
#define SA (-1.0f / 16.0f)        // A = SA*z   (power of 2, exact)
#define SB (32.0f)                // B = SB*w   -> A*B sums to -2 z.w

typedef _Float16 half8 __attribute__((ext_vector_type(8)));
typedef float f32x4 __attribute__((ext_vector_type(4)));

// ws: @0 pad | @8 uint flagcnt | @64 float ww[512] | @2112 bfrag (32768)
//     | @36864 double partials[2048] (16384) | @53248 int worklist[...]
#define STAGE_F4 2176             // (2048 + 32768) / 16
#define PART_OFF 36864
#define WL_OFF 53248
// LDS: ww @0 (2048) | bfrag @2048 (32768) | scratch @34816 (256*16) = 38912 B

__global__ void vq_prep(const float* __restrict__ cb, float* __restrict__ ww,
                        half8* __restrict__ bfrag, unsigned* __restrict__ flagcnt) {
    int gid = blockIdx.x * 256 + threadIdx.x;   // 8 x 256 = 2048
    if (gid == 0) *flagcnt = 0u;
    if (gid >= 2048) return;
    int t = gid >> 6, l = gid & 63;
    int code = t * 16 + (l & 15), koff = (l >> 4) * 8;
    const float* w = cb + (size_t)code * D + koff;
    half8 h;
#pragma unroll
    for (int j = 0; j < 8; ++j) h[j] = (_Float16)(SB * w[j]);
    bfrag[t * 64 + l] = h;                      // MFMA B-fragment lane order
    if (koff == 0) {                            // platonic ||w||^2 -> f32
        const float* wr = cb + (size_t)code * D;
        double s = 0.0;
#pragma unroll
        for (int d = 0; d < D; ++d) s = fma((double)wr[d], (double)wr[d], s);
        ww[code] = (float)s;
    }
}

__global__ __launch_bounds__(256, 3) void vq_main(
        const float* __restrict__ z, const float* __restrict__ cbf,
        const float4* __restrict__ stage_src,   // ws+64
        float* __restrict__ zq, float* __restrict__ idxo,
        double* __restrict__ partials, unsigned* __restrict__ flagcnt,
        int* __restrict__ worklist, int wl_cap) {
    __shared__ __align__(16) char smem[38912];
    __shared__ double wsum[4];
    const int tid = threadIdx.x;

    {   // stage ww + B-fragments into LDS
        float4* s4 = (float4*)smem;
#pragma unroll
        for (int i = 0; i < 9; ++i) {
            int k = i * 256 + tid;
            if (k < STAGE_F4) s4[k] = stage_src[k];
        }
    }

    const float* lds_ww = (const float*)smem;
    const char* lds_bf = smem + 2048;
    float4* scratch = (float4*)(smem + 34816);   // [256 rows] (m1, m2, idx, zz)

    const int l = tid & 63, wv = tid >> 6;
    const int g16 = l & 15, kg = l >> 4, koff = kg * 8;
    const int vblock = blockIdx.x * 256;         // block owns 256 rows

    __syncthreads();   // staging visible

#pragma unroll 1
    for (int mt = 0; mt < 4; ++mt) {
        const int rbase = wv * 64 + mt * 16;     // rows rbase..rbase+15 (in block)
        const float* zp = z + (size_t)(vblock + rbase + g16) * D + koff;
        float4 a0 = *(const float4*)zp;
        float4 a1 = *(const float4*)(zp + 4);
        half8 A;
        A[0] = (_Float16)(a0.x * SA); A[1] = (_Float16)(a0.y * SA);
        A[2] = (_Float16)(a0.z * SA); A[3] = (_Float16)(a0.w * SA);
        A[4] = (_Float16)(a1.x * SA); A[5] = (_Float16)(a1.y * SA);
        A[6] = (_Float16)(a1.z * SA); A[7] = (_Float16)(a1.w * SA);
        float ss = 0.f;
        ss = fmaf(a0.x, a0.x, ss); ss = fmaf(a0.y, a0.y, ss);
        ss = fmaf(a0.z, a0.z, ss); ss = fmaf(a0.w, a0.w, ss);
        ss = fmaf(a1.x, a1.x, ss); ss = fmaf(a1.y, a1.y, ss);
        ss = fmaf(a1.z, a1.z, ss); ss = fmaf(a1.w, a1.w, ss);
        ss += __shfl_xor(ss, 16, 64);            // sum the 4 koff chunks
        ss += __shfl_xor(ss, 32, 64);

        float m1[4], m2[4]; int i1[4];
#pragma unroll
        for (int r = 0; r < 4; ++r) { m1[r] = 1e30f; m2[r] = 1e30f; i1[r] = 0; }

#pragma unroll 4
        for (int t = 0; t < 32; ++t) {
            half8 B = *(const half8*)(lds_bf + t * 1024 + l * 16);
            float wwv = lds_ww[t * 16 + g16];
            int nl = t * 16 + g16;
            f32x4 acc = {wwv, wwv, wwv, wwv};    // C-init = ||w||^2 -> acc = score
            acc = __builtin_amdgcn_mfma_f32_16x16x32_f16(A, B, acc, 0, 0, 0);
#pragma unroll
            for (int r = 0; r < 4; ++r) {
                float s = acc[r];
                m2[r] = fminf(m2[r], fmaxf(s, m1[r]));
                bool c = s < m1[r];
                i1[r] = c ? nl : i1[r];
                m1[r] = fminf(m1[r], s);
            }
        }

        // reduce across the 16 code-lanes of each row-group
#pragma unroll
        for (int r = 0; r < 4; ++r) {
            float a1v = m1[r], a2v = m2[r]; int ai = i1[r];
#pragma unroll
            for (int dd = 1; dd <= 8; dd <<= 1) {
                float o1 = __shfl_xor(a1v, dd, 64);
                float o2 = __shfl_xor(a2v, dd, 64);
                int oi = __shfl_xor(ai, dd, 64);
                a2v = fminf(fminf(a2v, o2), fmaxf(a1v, o1));
                bool take = (o1 < a1v) || (o1 == a1v && oi < ai);
                ai = take ? oi : ai;
                a1v = fminf(a1v, o1);
            }
            m1[r] = a1v; m2[r] = a2v; i1[r] = ai;
        }

        // row table: row rbase + 4*kg + r  (holder lane g16==r)
#pragma unroll
        for (int r = 0; r < 4; ++r)
            if (g16 == r) {
                float* sp = (float*)&scratch[rbase + 4 * kg + r];
                sp[0] = m1[r]; sp[1] = m2[r]; sp[2] = __int_as_float(i1[r]);
            }
        if (kg == 0)
            ((float*)&scratch[rbase + g16])[3] = ss;   // ||z||^2
    }
    __syncthreads();

    // ---- epilogue (block scope; no f64 rescan, NO global atomics) ----
    float4 my = scratch[tid];                    // row tid of this block

    // near-tie rows -> global worklist (resolved by vq_fixup kernel)
    {
        bool flag = (my.y - my.x) <= MARGIN_TRIG;
        unsigned long long mask = __ballot(flag);
        if (mask) {
            int base = 0;
            if (l == 0) base = (int)atomicAdd(flagcnt, (unsigned)__popcll(mask));
            base = __shfl(base, 0, 64);
            if (flag) {
                int pos = base + (int)__popcll(mask & ((1ull << l) - 1ull));
                if (pos < wl_cap) worklist[pos] = vblock + tid;
            }
        }
    }

    // loss: ||z-q||^2 = ||z||^2 + s_win ; block-level reduce -> partials[bid]
    {
        double contrib = (double)my.x + (double)my.w;
#pragma unroll
        for (int off = 32; off; off >>= 1) contrib += __shfl_down(contrib, off, 64);
        if (l == 0) wsum[wv] = contrib;
    }
    __syncthreads();
    if (tid == 0) partials[blockIdx.x] = wsum[0] + wsum[1] + wsum[2] + wsum[3];

    // indices: 1KB contiguous per block
    idxo[vblock + tid] = (float)__float_as_int(my.z);
    // z_q: 256 threads x 8 iters cover 256 rows x 32 floats, fully contiguous
    {
        const float4* cb4 = (const float4*)cbf;
        float4* zq4 = (float4*)zq;
        const int c = tid & 7;
#pragma unroll
        for (int it = 0; it < 8; ++it) {
            int r = it * 32 + (tid >> 3);
            int win = __float_as_int(((const float*)scratch)[r * 4 + 2]);
            float4 val = cb4[(size_t)win * 8 + c];
            zq4[(size_t)(vblock + r) * 8 + c] = val;
        }
    }
}

// cold path: exact wave-parallel rescan of flagged rows (reg cap 256, z in regs)
__global__ __launch_bounds__(256, 2) void vq_fixup(
        const float* __restrict__ z, const float* __restrict__ cbf,
        const float* __restrict__ c32g,
        float* __restrict__ zq, float* __restrict__ idxo,
        const unsigned* __restrict__ flagcnt,
        const int* __restrict__ worklist, int wl_cap) {
    int cnt = (int)*flagcnt; if (cnt > wl_cap) cnt = wl_cap;
    const int l = threadIdx.x & 63;
    const int wave = (blockIdx.x * blockDim.x + threadIdx.x) >> 6;
    const int nwaves = (gridDim.x * blockDim.x) >> 6;

    for (int e = wave; e < cnt; e += nwaves) {
        int v = worklist[e];
        const float* zv = z + (size_t)v * D;        // uniform addr -> broadcast
        float4 zr[8];                               // hoist z once (32 regs)
#pragma unroll
        for (int q = 0; q < 8; ++q) zr[q] = *(const float4*)(zv + q * 4);
        double Ad = 0.0;
#pragma unroll
        for (int q = 0; q < 8; ++q) {
            Ad = fma((double)zr[q].x, (double)zr[q].x, Ad);
            Ad = fma((double)zr[q].y, (double)zr[q].y, Ad);
            Ad = fma((double)zr[q].z, (double)zr[q].z, Ad);
            Ad = fma((double)zr[q].w, (double)zr[q].w, Ad);
        }
        float Af = (float)Ad;
        float best = 1e30f; int bi = 0;
#pragma unroll 2
        for (int j = 0; j < 8; ++j) {
            int c = l * 8 + j;                      // lane-major => index-ordered
            const float* w = cbf + (size_t)c * D;
            double bd = 0.0;
#pragma unroll
            for (int q = 0; q < 8; ++q) {
                float4 wq = *(const float4*)(w + q * 4);
                bd = fma((double)zr[q].x, (double)wq.x, bd);
                bd = fma((double)zr[q].y, (double)wq.y, bd);
                bd = fma((double)zr[q].z, (double)wq.z, bd);
                bd = fma((double)zr[q].w, (double)wq.w, bd);
            }
            float B32 = (float)bd;                  // platonic dot
            float dq = __fadd_rn(__fsub_rn(Af, __fmul_rn(2.0f, B32)), c32g[c]);
            if (dq < best) { best = dq; bi = c; }
        }
#pragma unroll
        for (int dd = 1; dd < 64; dd <<= 1) {
            float ob = __shfl_xor(best, dd, 64);
            int obi = __shfl_xor(bi, dd, 64);
            bool take = (ob < best) || (ob == best && obi < bi);
            best = take ? ob : best; bi = take ? obi : bi;
        }
        if (l == 0) idxo[v] = (float)bi;
        if (l < 8) {                                // one full 128B line
            float4 val = ((const float4*)cbf)[(size_t)bi * 8 + l];
            ((float4*)zq)[(size_t)v * 8 + l] = val;
        }
    }
}

__global__ __launch_bounds__(256) void vq_final(
        const double* __restrict__ partials, float* __restrict__ loss_out) {
    const int tid = threadIdx.x;
    double s = 0.0;
#pragma unroll
    for (int i = 0; i < NBLK / 256; ++i) s += partials[i * 256 + tid];
#pragma unroll
    for (int off = 32; off; off >>= 1) s += __shfl_down(s, off, 64);
    __shared__ double w4[4];
    if ((tid & 63) == 0) w4[tid >> 6] = s;
    __syncthreads();
    if (tid == 0) {
        double t = w4[0] + w4[1] + w4[2] + w4[3];
        *loss_out = (float)(1.25 * t / (double)ZQ_ELEMS);
    }
}

extern "C" void kernel_launch(void* const* d_in, const int* in_sizes, int n_in,
                              void* d_out, int out_size, void* d_ws, size_t ws_size,
                              hipStream_t stream) {
    const float* z  = (const float*)d_in[0];
    const float* cb = (const float*)d_in[1];
    float* out  = (float*)d_out;
    float* zq   = out;
    float* idxo = out + ZQ_ELEMS;
    float* loss = out + ZQ_ELEMS + NVEC;
    unsigned* flagcnt = (unsigned*)((char*)d_ws + 8);
    float*    ww      = (float*)((char*)d_ws + 64);
    half8*    bfrag   = (half8*)((char*)d_ws + 2112);
    const float4* stage_src = (const float4*)((char*)d_ws + 64);
    double*   partials = (double*)((char*)d_ws + PART_OFF);
    int*      worklist = (int*)((char*)d_ws + WL_OFF);
    long long avail = (long long)ws_size - WL_OFF;
    int wl_cap = avail > 0 ? (int)(avail / 4 < NVEC ? avail / 4 : NVEC) : 0;

    vq_prep<<<8, 256, 0, stream>>>(cb, ww, bfrag, flagcnt);
    vq_main<<<NBLK, 256, 0, stream>>>(z, cb, stage_src, zq, idxo,
                                      partials, flagcnt, worklist, wl_cap);
    vq_fixup<<<256, 256, 0, stream>>>(z, cb, ww, zq, idxo, flagcnt, worklist, wl_cap);
    vq_final<<<1, 256, 0, stream>>>(partials, loss);
}